// Round 1
// baseline (1867.489 us; speedup 1.0000x reference)
//
#include <hip/hip_runtime.h>
#include <hip/hip_bf16.h>
#include <math.h>

#define B   16
#define S   4096
#define D   2048
#define H   16
#define HD  128
#define DFF 8192
#define EPS 1e-5f

#define NC  32    // attention S-chunks per head
#define CH  128   // chunk size (last chunk gets +1 for the new token)

// ---------------------------------------------------------------------------
// Skinny GEMV: out(16,N) += x(16,K) @ W(K,N). K split across blockIdx.y,
// accumulated with atomicAdd. Thread = one column, 16 batch accumulators.
// x reads are wave-uniform -> scalar loads; W reads coalesced streaming.
// ---------------------------------------------------------------------------
__global__ __launch_bounds__(256) void gemv16_atomic(
    const float* __restrict__ x, const float* __restrict__ W,
    float* __restrict__ out, int K, int N, int kchunk)
{
    int j  = blockIdx.x * 256 + threadIdx.x;
    int k0 = blockIdx.y * kchunk;
    float acc[16];
#pragma unroll
    for (int b = 0; b < 16; ++b) acc[b] = 0.f;
    const float* Wp = W + (size_t)k0 * N + j;
    for (int k = 0; k < kchunk; ++k) {
        float w = Wp[(size_t)k * N];
#pragma unroll
        for (int b = 0; b < 16; ++b)
            acc[b] = fmaf(x[b * K + k0 + k], w, acc[b]);
    }
#pragma unroll
    for (int b = 0; b < 16; ++b)
        atomicAdd(&out[(size_t)b * N + j], acc[b]);
}

// out[0..32767] = b2 broadcast (bias init for W2 GEMV),
// out[32768..65535] = residual (init for Wo GEMV -> residual_out)
__global__ __launch_bounds__(256) void init_out_kernel(
    const float* __restrict__ residual, const float* __restrict__ b2,
    float* __restrict__ out)
{
    int i = blockIdx.x * 256 + threadIdx.x;      // 0..32767
    out[i] = b2[i & (D - 1)];
    out[B * D + i] = residual[i];
}

// Per-batch head router + top-k(=8 of 16) mask. Stable ties (lower index wins).
__global__ __launch_bounds__(256) void head_mask_kernel(
    const float* __restrict__ x, const float* __restrict__ Wr,
    const int* __restrict__ topk_ptr, float* __restrict__ hmask)
{
    __shared__ float part[256];
    __shared__ float logit[16];
    int b = blockIdx.x, tid = threadIdx.x;
    int h = tid >> 4, t = tid & 15;
    float s = 0.f;
    for (int k = t; k < D; k += 16) s += x[b * D + k] * Wr[k * H + h];
    part[tid] = s;
    __syncthreads();
    if (tid < 16) {
        float v = 0.f;
        for (int t2 = 0; t2 < 16; ++t2) v += part[tid * 16 + t2];
        logit[tid] = v;
    }
    __syncthreads();
    if (tid < 16) {
        int k = topk_ptr[0];
        float v = logit[tid];
        int rank = 0;
        for (int i = 0; i < 16; ++i) {
            float vi = logit[i];
            if (vi > v || (vi == v && i < tid)) rank++;
        }
        hmask[b * H + tid] = (rank < k) ? 1.f : 0.f;
    }
}

__device__ __forceinline__ int block_reduce_sum_i(int v, int* lds)
{
    for (int off = 32; off; off >>= 1) v += __shfl_xor(v, off);
    int wid = threadIdx.x >> 6;
    if ((threadIdx.x & 63) == 0) lds[wid] = v;
    __syncthreads();
    int total = lds[0] + lds[1] + lds[2] + lds[3];
    __syncthreads();
    return total;
}

// Per-batch neuron top-k (2048 of 8192) via bitwise radix-select on the
// order-preserving uint transform; stable tie handling by index.
__global__ __launch_bounds__(256) void neuron_mask_kernel(
    const float* __restrict__ logits, const int* __restrict__ topk_ptr,
    float* __restrict__ nmask)
{
    __shared__ unsigned int u[DFF];   // 32 KB
    __shared__ int redi[4];
    __shared__ int scan[256];
    int b = blockIdx.x, tid = threadIdx.x;
    const float* lg = logits + (size_t)b * DFF;
    for (int j = tid; j < DFF; j += 256) {
        unsigned int bits = __float_as_uint(lg[j]);
        u[j] = (bits & 0x80000000u) ? ~bits : (bits | 0x80000000u);
    }
    __syncthreads();
    int k = topk_ptr[0];
    int j0 = tid * 32, j1 = j0 + 32;

    unsigned int prefix = 0;
    for (int bit = 31; bit >= 0; --bit) {
        unsigned int test = prefix | (1u << bit);
        int c = 0;
        for (int j = j0; j < j1; ++j) c += (u[j] >= test);
        c = block_reduce_sum_i(c, redi);
        if (c >= k) prefix = test;   // uniform across block
    }
    // prefix == k-th largest key
    int cgt = 0, ceq = 0;
    for (int j = j0; j < j1; ++j) { cgt += (u[j] > prefix); ceq += (u[j] == prefix); }
    cgt = block_reduce_sum_i(cgt, redi);
    int rem = k - cgt;
    // inclusive scan of per-thread equal-counts -> stable tie assignment
    scan[tid] = ceq;
    __syncthreads();
    for (int off = 1; off < 256; off <<= 1) {
        int v = scan[tid];
        int add = (tid >= off) ? scan[tid - off] : 0;
        __syncthreads();
        scan[tid] = v + add;
        __syncthreads();
    }
    int excl = scan[tid] - ceq;
    float* nm = nmask + (size_t)b * DFF;
    int seen = 0;
    for (int j = j0; j < j1; ++j) {
        float m;
        if (u[j] > prefix) m = 1.f;
        else if (u[j] == prefix) { m = (excl + seen < rem) ? 1.f : 0.f; seen++; }
        else m = 0.f;
        nm[j] = m;
    }
}

// Split-K decode attention partial: per (b, h, chunk) compute local max m,
// sumexp l, and weighted-V partial (128 floats). Masked heads skip all reads.
__global__ __launch_bounds__(256) void attn_partial_kernel(
    const float* __restrict__ qkv, const float* __restrict__ k_cache,
    const float* __restrict__ v_cache, const float* __restrict__ hmask,
    float* __restrict__ part)
{
    int blk = blockIdx.x;
    int c   = blk & (NC - 1);
    int bh  = blk >> 5;           // NC == 32
    int h   = bh & (H - 1);
    int b   = bh >> 4;
    if (hmask[bh] == 0.f) return;

    int tid = threadIdx.x;
    int lane = tid & 63, w = tid >> 6;
    int start = c * CH;
    int n = (c == NC - 1) ? (S + 1 - start) : CH;   // last chunk: 129

    __shared__ float sc[CH + 1];
    __shared__ float redf[4];
    __shared__ float vred[256];

    const float* qp = qkv + ((size_t)b * 3 + 0) * D + h * HD;
    float2 q2 = ((const float2*)qp)[lane];
    const float scale = 0.08838834764831845f;   // 1/sqrt(128)

    // Phase A: scores -> LDS (wave per row, float2 per lane, butterfly reduce)
    for (int sl = w; sl < n; sl += 4) {
        int s = start + sl;
        const float* kp = (s < S)
            ? (k_cache + (((size_t)b * S + s) * H + h) * HD)
            : (qkv + ((size_t)b * 3 + 1) * D + h * HD);
        float2 k2 = ((const float2*)kp)[lane];
        float p = fmaf(q2.x, k2.x, q2.y * k2.y);
#pragma unroll
        for (int off = 32; off; off >>= 1) p += __shfl_xor(p, off);
        if (lane == 0) sc[sl] = p * scale;
    }
    __syncthreads();

    // Phase B: local max, exp, sum
    float lm = -INFINITY;
    for (int i = tid; i < n; i += 256) lm = fmaxf(lm, sc[i]);
    for (int off = 32; off; off >>= 1) lm = fmaxf(lm, __shfl_xor(lm, off));
    if (lane == 0) redf[w] = lm;
    __syncthreads();
    float m = fmaxf(fmaxf(redf[0], redf[1]), fmaxf(redf[2], redf[3]));
    __syncthreads();
    float ls = 0.f;
    for (int i = tid; i < n; i += 256) {
        float p = __expf(sc[i] - m);
        sc[i] = p;
        ls += p;
    }
    for (int off = 32; off; off >>= 1) ls += __shfl_xor(ls, off);
    if (lane == 0) redf[w] = ls;
    __syncthreads();
    float l = redf[0] + redf[1] + redf[2] + redf[3];

    // Phase C: ctx_partial[d] = sum_s p_s * V[s][d]; 2 thread-groups over s
    int d = tid & 127, g = tid >> 7;
    float acc = 0.f;
    for (int i = g; i < n; i += 2) {
        int s = start + i;
        const float* vp = (s < S)
            ? (v_cache + (((size_t)b * S + s) * H + h) * HD)
            : (qkv + ((size_t)b * 3 + 2) * D + h * HD);
        acc = fmaf(sc[i], vp[d], acc);
    }
    vred[tid] = acc;
    __syncthreads();
    float* pp = part + ((size_t)bh * NC + c) * (HD + 2);
    if (tid < 128) pp[tid] = vred[tid] + vred[tid + 128];
    if (tid == 0) { pp[HD] = m; pp[HD + 1] = l; }
}

// Combine chunk partials with global softmax rescale; apply head mask.
__global__ __launch_bounds__(128) void attn_combine_kernel(
    const float* __restrict__ part, const float* __restrict__ hmask,
    float* __restrict__ ctx)
{
    int bh = blockIdx.x, d = threadIdx.x;
    float* o = ctx + (size_t)bh * HD;   // (B, H*HD) layout
    if (hmask[bh] == 0.f) { o[d] = 0.f; return; }
    const float* pp = part + (size_t)bh * NC * (HD + 2);
    float M = -INFINITY;
    for (int c = 0; c < NC; ++c) M = fmaxf(M, pp[c * (HD + 2) + HD]);
    float L = 0.f, acc = 0.f;
    for (int c = 0; c < NC; ++c) {
        float s = __expf(pp[c * (HD + 2) + HD] - M);
        L += pp[c * (HD + 2) + HD + 1] * s;
        acc = fmaf(pp[c * (HD + 2) + d], s, acc);
    }
    o[d] = acc / L;
}

__global__ __launch_bounds__(256) void layernorm_kernel(
    const float* __restrict__ res, const float* __restrict__ w,
    const float* __restrict__ bb, float* __restrict__ hout)
{
    int b = blockIdx.x, tid = threadIdx.x;
    const float* xr = res + (size_t)b * D;
    float s = 0.f, s2 = 0.f;
    for (int j = tid; j < D; j += 256) { float v = xr[j]; s += v; s2 += v * v; }
    for (int off = 32; off; off >>= 1) { s += __shfl_xor(s, off); s2 += __shfl_xor(s2, off); }
    __shared__ float r1[4], r2[4];
    if ((tid & 63) == 0) { r1[tid >> 6] = s; r2[tid >> 6] = s2; }
    __syncthreads();
    float mu  = (r1[0] + r1[1] + r1[2] + r1[3]) / D;
    float var = (r2[0] + r2[1] + r2[2] + r2[3]) / D - mu * mu;
    float inv = rsqrtf(var + EPS);
    float* ho = hout + (size_t)b * D;
    for (int j = tid; j < D; j += 256) ho[j] = (xr[j] - mu) * inv * w[j] + bb[j];
}

__global__ __launch_bounds__(256) void relu_mask_kernel(
    const float* __restrict__ z, const float* __restrict__ b1,
    const float* __restrict__ nmask, float* __restrict__ a)
{
    int i = blockIdx.x * 256 + threadIdx.x;   // B*DFF
    int j = i & (DFF - 1);
    a[i] = nmask[i] * fmaxf(z[i] + b1[j], 0.f);
}

extern "C" void kernel_launch(void* const* d_in, const int* in_sizes, int n_in,
                              void* d_out, int out_size, void* d_ws, size_t ws_size,
                              hipStream_t stream)
{
    const float* hidden   = (const float*)d_in[0];
    const float* residual = (const float*)d_in[1];
    const float* k_cache  = (const float*)d_in[2];
    const float* v_cache  = (const float*)d_in[3];
    const float* Wqkv     = (const float*)d_in[4];
    const float* Wo       = (const float*)d_in[5];
    const float* Wmha     = (const float*)d_in[6];
    const float* Wmlp     = (const float*)d_in[7];
    const float* W1       = (const float*)d_in[8];
    const float* b1       = (const float*)d_in[9];
    const float* W2       = (const float*)d_in[10];
    const float* b2       = (const float*)d_in[11];
    const float* n2w      = (const float*)d_in[12];
    const float* n2b      = (const float*)d_in[13];
    const int* mlp_topk   = (const int*)d_in[14];
    const int* attn_topk  = (const int*)d_in[15];
    float* out = (float*)d_out;

    float* ws     = (float*)d_ws;
    float* qkv    = ws;              // 16*6144          =  98304
    float* mlplog = ws + 98304;      // 16*8192          = 131072
    float* z      = ws + 229376;     // 16*8192          = 131072
    float* nmask  = ws + 360448;     // 16*8192          = 131072
    float* hmask  = ws + 491520;     // 256
    float* ctx    = ws + 491776;     // 16*2048          =  32768
    float* hbuf   = ws + 524544;     // 16*2048          =  32768
    float* abuf   = ws + 557312;     // 16*8192          = 131072
    float* part   = ws + 688384;     // 16*16*32*130     = 1064960
    // total 1,753,344 floats ≈ 6.7 MB

    // zero the three atomically-accumulated buffers (qkv, mlplog, z)
    hipMemsetAsync(ws, 0, (size_t)360448 * sizeof(float), stream);

    init_out_kernel<<<128, 256, 0, stream>>>(residual, b2, out);

    gemv16_atomic<<<dim3(3 * D / 256, 8), 256, 0, stream>>>(hidden, Wqkv, qkv, D, 3 * D, 256);
    gemv16_atomic<<<dim3(DFF / 256, 8), 256, 0, stream>>>(hidden, Wmlp, mlplog, D, DFF, 256);
    head_mask_kernel<<<B, 256, 0, stream>>>(hidden, Wmha, attn_topk, hmask);
    neuron_mask_kernel<<<B, 256, 0, stream>>>(mlplog, mlp_topk, nmask);

    attn_partial_kernel<<<B * H * NC, 256, 0, stream>>>(qkv, k_cache, v_cache, hmask, part);
    attn_combine_kernel<<<B * H, 128, 0, stream>>>(part, hmask, ctx);

    gemv16_atomic<<<dim3(D / 256, 32), 256, 0, stream>>>(ctx, Wo, out + B * D, D, D, 64);
    layernorm_kernel<<<B, 256, 0, stream>>>(out + B * D, n2w, n2b, hbuf);

    gemv16_atomic<<<dim3(DFF / 256, 8), 256, 0, stream>>>(hbuf, W1, z, D, DFF, 256);
    relu_mask_kernel<<<B * DFF / 256, 256, 0, stream>>>(z, b1, nmask, abuf);
    gemv16_atomic<<<dim3(D / 256, 32), 256, 0, stream>>>(abuf, W2, out, DFF, D, 256);
}